// Round 1
// baseline (1606.862 us; speedup 1.0000x reference)
//
#include <hip/hip_runtime.h>
#include <hip/hip_bf16.h>

// -------------------- helpers --------------------

__device__ __forceinline__ float wave_sum64(float v) {
#pragma unroll
    for (int off = 1; off < 64; off <<= 1) v += __shfl_xor(v, off, 64);
    return v;
}

// -------------------- GEMM + leaky + l2norm --------------------
// features[NI,DF] @ W[DF,64] + b -> leaky_relu -> l2norm rows -> x[NU+i]
// block: 256 thr = 16 tc x 16 tr; block tile 128 rows x 64 cols; thread tile 8x4.
__global__ __launch_bounds__(256) void k_gemm(const float* __restrict__ A,
                                              const float* __restrict__ W,
                                              const float* __restrict__ Bb,
                                              float* __restrict__ x,
                                              int NI, int DF, int NU) {
    __shared__ float wt[32][64];
    const int tid = threadIdx.x;
    const int tc = tid & 15, tr = tid >> 4;
    const int row0 = blockIdx.x * 128;
    const int c0 = tc * 4;

    float acc[8][4];
#pragma unroll
    for (int r = 0; r < 8; ++r)
#pragma unroll
        for (int c = 0; c < 4; ++c) acc[r][c] = 0.f;

    int rows[8];
#pragma unroll
    for (int rr = 0; rr < 8; ++rr) {
        int r = row0 + tr * 8 + rr;
        rows[rr] = r < NI ? r : NI - 1;  // clamp (results discarded on store)
    }

    for (int k0 = 0; k0 < DF; k0 += 32) {
        __syncthreads();
#pragma unroll
        for (int j = 0; j < 8; ++j) {
            int idx = tid + j * 256;
            wt[idx >> 6][idx & 63] = W[(size_t)(k0 + (idx >> 6)) * 64 + (idx & 63)];
        }
        __syncthreads();
#pragma unroll
        for (int kk = 0; kk < 32; kk += 4) {
            float b[4][4];
#pragma unroll
            for (int i = 0; i < 4; ++i)
                *(float4*)b[i] = *(const float4*)&wt[kk + i][c0];
#pragma unroll
            for (int rr = 0; rr < 8; ++rr) {
                float a[4];
                *(float4*)a = *(const float4*)&A[(size_t)rows[rr] * DF + k0 + kk];
#pragma unroll
                for (int i = 0; i < 4; ++i)
#pragma unroll
                    for (int c = 0; c < 4; ++c)
                        acc[rr][c] = fmaf(a[i], b[i][c], acc[rr][c]);
            }
        }
    }

    float bias[4];
    *(float4*)bias = *(const float4*)&Bb[c0];

#pragma unroll
    for (int rr = 0; rr < 8; ++rr) {
        int r = row0 + tr * 8 + rr;
        float v[4];
#pragma unroll
        for (int c = 0; c < 4; ++c) {
            float t = acc[rr][c] + bias[c];
            v[c] = t >= 0.f ? t : 0.01f * t;  // leaky_relu
        }
        float ss = v[0] * v[0] + v[1] * v[1] + v[2] * v[2] + v[3] * v[3];
#pragma unroll
        for (int off = 1; off < 16; off <<= 1) ss += __shfl_xor(ss, off, 64);
        float scale = 1.f / fmaxf(sqrtf(ss), 1e-12f);
        if (r < NI) {
            float4 o;
            o.x = v[0] * scale; o.y = v[1] * scale; o.z = v[2] * scale; o.w = v[3] * scale;
            *(float4*)&x[(size_t)(NU + r) * 64 + c0] = o;
        }
    }
}

// -------------------- l2norm(preference) -> x[0..NU) --------------------
__global__ __launch_bounds__(256) void k_prefnorm(const float* __restrict__ P,
                                                  float* __restrict__ x, int NU) {
    int u = (int)((blockIdx.x * blockDim.x + threadIdx.x) >> 6);
    int lane = threadIdx.x & 63;
    if (u >= NU) return;
    float v = P[(size_t)u * 64 + lane];
    float ss = wave_sum64(v * v);
    x[(size_t)u * 64 + lane] = v / fmaxf(sqrtf(ss), 1e-12f);
}

// -------------------- CSR build --------------------
__global__ void k_hist(const int* __restrict__ dst, int E, int* __restrict__ deg) {
    int e = blockIdx.x * blockDim.x + threadIdx.x;
    if (e < E) atomicAdd(&deg[dst[e]], 1);
}

__global__ void k_scan_sums(const int* __restrict__ deg, int m, int* __restrict__ sums) {
    __shared__ int sm[256];
    int t = threadIdx.x;
    int base = blockIdx.x * 2048 + t * 8;
    int s = 0;
#pragma unroll
    for (int i = 0; i < 8; ++i) {
        int idx = base + i;
        if (idx < m) s += deg[idx];
    }
    sm[t] = s;
    __syncthreads();
    for (int off = 128; off > 0; off >>= 1) {
        if (t < off) sm[t] += sm[t + off];
        __syncthreads();
    }
    if (t == 0) sums[blockIdx.x] = sm[0];
}

__global__ void k_scan_offsets(int* __restrict__ sums, int nb, int* __restrict__ rp_last) {
    if (threadIdx.x == 0 && blockIdx.x == 0) {
        int run = 0;
        for (int i = 0; i < nb; ++i) { int t = sums[i]; sums[i] = run; run += t; }
        *rp_last = run;
    }
}

__global__ void k_scan_apply(const int* __restrict__ deg, int m, const int* __restrict__ sums,
                             int* __restrict__ rp, int* __restrict__ cur) {
    __shared__ int sm[256];
    int t = threadIdx.x;
    int base = blockIdx.x * 2048 + t * 8;
    int v[8];
    int s = 0;
#pragma unroll
    for (int i = 0; i < 8; ++i) {
        int idx = base + i;
        v[i] = (idx < m) ? deg[idx] : 0;
        s += v[i];
    }
    sm[t] = s;
    __syncthreads();
    for (int off = 1; off < 256; off <<= 1) {
        int add = (t >= off) ? sm[t - off] : 0;
        __syncthreads();
        sm[t] += add;
        __syncthreads();
    }
    int run = sums[blockIdx.x] + sm[t] - s;  // exclusive base for this thread
#pragma unroll
    for (int i = 0; i < 8; ++i) {
        int idx = base + i;
        if (idx < m) { rp[idx] = run; cur[idx] = run; run += v[i]; }
    }
}

__global__ void k_scatter(const int* __restrict__ dst, const int* __restrict__ src, int E,
                          int* __restrict__ cur, int* __restrict__ out_src,
                          int* __restrict__ out_eid) {
    int e = blockIdx.x * blockDim.x + threadIdx.x;
    if (e >= E) return;
    int d = dst[e];
    int slot = atomicAdd(&cur[d], 1);
    out_src[slot] = src[e];
    if (out_eid) out_eid[slot] = e;
}

// -------------------- user routing (in-place, fused residual+l2norm) ------
// one wave per user; lane = feature dim. srcs are all item rows (never written).
__global__ __launch_bounds__(256) void k_refine_user(float* __restrict__ x,
                                                     const int* __restrict__ rp,
                                                     const int* __restrict__ srcs, int NU) {
    int u = (int)((blockIdx.x * blockDim.x + threadIdx.x) >> 6);
    int lane = threadIdx.x & 63;
    if (u >= NU) return;
    float xd = x[(size_t)u * 64 + lane];
    int j0 = rp[u], j1 = rp[u + 1];
    float s = 0.f, acc = 0.f;
    for (int j = j0; j < j1; ++j) {
        int sc = srcs[j];
        float xs = x[(size_t)sc * 64 + lane];
        float dot = wave_sum64(xd * xs);  // rows are unit vectors: cos sim
        float e = __expf(dot);            // max-shift is a mathematical no-op here
        s += e;
        acc += e * xs;
    }
    float v = xd + acc / (s + 1e-16f);
    float ss = wave_sum64(v * v);
    x[(size_t)u * 64 + lane] = v / fmaxf(sqrtf(ss), 1e-12f);
}

// -------------------- final refine over full adj --------------------
__global__ __launch_bounds__(256) void k_refine_final(const float* __restrict__ x,
                                                      const int* __restrict__ rp,
                                                      const int* __restrict__ srcs,
                                                      const int* __restrict__ eids, int n,
                                                      float* __restrict__ out,
                                                      float* __restrict__ alpha,
                                                      float* __restrict__ sinv) {
    int d = (int)((blockIdx.x * blockDim.x + threadIdx.x) >> 6);
    int lane = threadIdx.x & 63;
    if (d >= n) return;
    float xd = x[(size_t)d * 64 + lane];
    int j0 = rp[d], j1 = rp[d + 1];
    float s = 0.f, acc = 0.f;
    for (int j = j0; j < j1; ++j) {
        int sc = srcs[j];
        float xs = x[(size_t)sc * 64 + lane];
        float dot = wave_sum64(xd * xs);
        float e = __expf(dot);
        s += e;
        acc += e * xs;
        if (lane == 0) alpha[eids[j]] = e;  // unscaled; scaled by k_alpha_scale
    }
    float inv = 1.f / (s + 1e-16f);
    if (lane == 0) sinv[d] = inv;
    float xh = acc * inv;
    xh = xh >= 0.f ? xh : 0.01f * xh;  // leaky_relu on x_hat
    out[(size_t)d * 64 + lane] = xd + xh;
}

__global__ void k_alpha_scale(float* __restrict__ alpha, const int* __restrict__ adj_dst,
                              const float* __restrict__ sinv, int E) {
    int e = blockIdx.x * blockDim.x + threadIdx.x;
    if (e < E) alpha[e] *= sinv[adj_dst[e]];
}

// -------------------- orchestration --------------------
extern "C" void kernel_launch(void* const* d_in, const int* in_sizes, int n_in,
                              void* d_out, int out_size, void* d_ws, size_t ws_size,
                              hipStream_t stream) {
    const float* features = (const float*)d_in[0];
    const float* mlp_w    = (const float*)d_in[1];
    const float* mlp_b    = (const float*)d_in[2];
    const float* pref     = (const float*)d_in[3];
    const int*   adj      = (const int*)d_in[4];
    const int*   adj_u    = (const int*)d_in[5];

    const int DC = in_sizes[2];        // 64
    const int DF = in_sizes[1] / DC;   // 2048
    const int NI = in_sizes[0] / DF;   // 30000
    const int NU = in_sizes[3] / DC;   // 50000
    const int E2 = in_sizes[4] / 2;    // 2,000,000
    const int EU = in_sizes[5] / 2;    // 1,000,000
    const int n  = NU + NI;            // 80000

    // workspace layout (all 4-byte elements)
    char* w = (char*)d_ws;
    float* x      = (float*)w; w += (size_t)n * 64 * 4;
    int* csr_su   = (int*)w;   w += (size_t)EU * 4;
    int* csr_sf   = (int*)w;   w += (size_t)E2 * 4;
    int* csr_ef   = (int*)w;   w += (size_t)E2 * 4;
    int* rp_u     = (int*)w;   w += (size_t)(NU + 1) * 4;
    int* rp_f     = (int*)w;   w += (size_t)(n + 1) * 4;
    int* cur_u    = (int*)w;   w += (size_t)NU * 4;
    int* cur_f    = (int*)w;   w += (size_t)n * 4;
    int* deg_u    = (int*)w;   w += (size_t)NU * 4;
    int* deg_f    = (int*)w;   w += (size_t)n * 4;
    int* sums     = (int*)w;   w += 64 * 4;
    float* sinv   = (float*)w; w += (size_t)n * 4;

    hipMemsetAsync(deg_u, 0, (size_t)NU * 4, stream);
    hipMemsetAsync(deg_f, 0, (size_t)n * 4, stream);

    // item features: GEMM + leaky + l2norm -> x[NU..n)
    k_gemm<<<(NI + 127) / 128, 256, 0, stream>>>(features, mlp_w, mlp_b, x, NI, DF, NU);
    // users: l2norm(pref) -> x[0..NU)
    k_prefnorm<<<(NU + 3) / 4, 256, 0, stream>>>(pref, x, NU);

    // degree histograms (dst = row 0 of each adjacency)
    k_hist<<<(EU + 255) / 256, 256, 0, stream>>>(adj_u, EU, deg_u);
    k_hist<<<(E2 + 255) / 256, 256, 0, stream>>>(adj, E2, deg_f);

    // CSR for adj_user (user dsts)
    int nb_u = (NU + 2047) / 2048;
    k_scan_sums<<<nb_u, 256, 0, stream>>>(deg_u, NU, sums);
    k_scan_offsets<<<1, 64, 0, stream>>>(sums, nb_u, rp_u + NU);
    k_scan_apply<<<nb_u, 256, 0, stream>>>(deg_u, NU, sums, rp_u, cur_u);
    k_scatter<<<(EU + 255) / 256, 256, 0, stream>>>(adj_u, adj_u + EU, EU, cur_u, csr_su, nullptr);

    // CSR for full adj (all dsts)
    int nb_f = (n + 2047) / 2048;
    k_scan_sums<<<nb_f, 256, 0, stream>>>(deg_f, n, sums);
    k_scan_offsets<<<1, 64, 0, stream>>>(sums, nb_f, rp_f + n);
    k_scan_apply<<<nb_f, 256, 0, stream>>>(deg_f, n, sums, rp_f, cur_f);
    k_scatter<<<(E2 + 255) / 256, 256, 0, stream>>>(adj, adj + E2, E2, cur_f, csr_sf, csr_ef);

    // 3 routing iterations (in-place on user rows of x)
    for (int it = 0; it < 3; ++it)
        k_refine_user<<<(NU + 3) / 4, 256, 0, stream>>>(x, rp_u, csr_su, NU);

    // final refine + outputs
    float* out   = (float*)d_out;
    float* alpha = out + (size_t)n * 64;
    k_refine_final<<<(n + 3) / 4, 256, 0, stream>>>(x, rp_f, csr_sf, csr_ef, n, out, alpha, sinv);
    k_alpha_scale<<<(E2 + 255) / 256, 256, 0, stream>>>(alpha, adj, sinv, E2);
}

// Round 3
// 1038.374 us; speedup vs baseline: 1.5475x; 1.5475x over previous
//
#include <hip/hip_runtime.h>
#include <hip/hip_bf16.h>

// -------------------- helpers --------------------

__device__ __forceinline__ float group16_sum(float v) {
    v += __shfl_xor(v, 1, 64);
    v += __shfl_xor(v, 2, 64);
    v += __shfl_xor(v, 4, 64);
    v += __shfl_xor(v, 8, 64);
    return v;
}

// -------------------- GEMM + leaky + l2norm --------------------
// features[NI,DF] @ W[DF,64] + b -> leaky_relu -> l2norm rows -> x[NU+i]
// block 256 thr; tile 64 rows x 64 cols; K-chunk 32; thread tile 4x4.
// A staged in LDS (coalesced), W chunk in LDS.
__global__ __launch_bounds__(256) void k_gemm(const float* __restrict__ A,
                                              const float* __restrict__ W,
                                              const float* __restrict__ Bb,
                                              float* __restrict__ x,
                                              int NI, int DF, int NU) {
    __shared__ float Ws[32][64];
    __shared__ float As[64][36];  // pad 32->36: conflict-free b128 reads for rows rr*16+tr
    const int tid = threadIdx.x;
    const int tc = tid & 15, tr = tid >> 4;
    const int row0 = blockIdx.x * 64;
    const int c0 = tc * 4;

    float acc[4][4];
#pragma unroll
    for (int r = 0; r < 4; ++r)
#pragma unroll
        for (int c = 0; c < 4; ++c) acc[r][c] = 0.f;

    for (int k0 = 0; k0 < DF; k0 += 32) {
        __syncthreads();
        // W chunk: 32x64 = 512 float4, 2 per thread
#pragma unroll
        for (int p = 0; p < 2; ++p) {
            int idx = p * 256 + tid;           // float4 id
            int r = idx >> 4, c4 = (idx & 15) * 4;
            *(float4*)&Ws[r][c4] = *(const float4*)&W[(size_t)(k0 + r) * 64 + c4];
        }
        // A chunk: 64 rows x 32 cols = 512 float4, 2 per thread, coalesced
#pragma unroll
        for (int p = 0; p < 2; ++p) {
            int lin = p * 256 + tid;           // float4 id
            int r = lin >> 3, c4 = (lin & 7) * 4;
            int gr = row0 + r;
            if (gr >= NI) gr = NI - 1;
            *(float4*)&As[r][c4] = *(const float4*)&A[(size_t)gr * DF + k0 + c4];
        }
        __syncthreads();
#pragma unroll
        for (int kk = 0; kk < 32; kk += 4) {
            float b[4][4];
#pragma unroll
            for (int i = 0; i < 4; ++i)
                *(float4*)b[i] = *(const float4*)&Ws[kk + i][c0];
#pragma unroll
            for (int rr = 0; rr < 4; ++rr) {
                float a[4];
                *(float4*)a = *(const float4*)&As[rr * 16 + tr][kk];
#pragma unroll
                for (int i = 0; i < 4; ++i)
#pragma unroll
                    for (int c = 0; c < 4; ++c)
                        acc[rr][c] = fmaf(a[i], b[i][c], acc[rr][c]);
            }
        }
    }

    float bias[4];
    *(float4*)bias = *(const float4*)&Bb[c0];

#pragma unroll
    for (int rr = 0; rr < 4; ++rr) {
        int gr = row0 + rr * 16 + tr;
        float v[4];
#pragma unroll
        for (int c = 0; c < 4; ++c) {
            float t = acc[rr][c] + bias[c];
            v[c] = t >= 0.f ? t : 0.01f * t;  // leaky_relu
        }
        float ss = v[0] * v[0] + v[1] * v[1] + v[2] * v[2] + v[3] * v[3];
#pragma unroll
        for (int off = 1; off < 16; off <<= 1) ss += __shfl_xor(ss, off, 64);
        float scale = 1.f / fmaxf(sqrtf(ss), 1e-12f);
        if (gr < NI) {
            float4 o;
            o.x = v[0] * scale; o.y = v[1] * scale; o.z = v[2] * scale; o.w = v[3] * scale;
            *(float4*)&x[(size_t)(NU + gr) * 64 + c0] = o;
        }
    }
}

// -------------------- CSR build --------------------
__global__ void k_hist(const int* __restrict__ dst, int E, int* __restrict__ deg) {
    int e = blockIdx.x * blockDim.x + threadIdx.x;
    if (e < E) atomicAdd(&deg[dst[e]], 1);
}

__global__ void k_scan_sums(const int* __restrict__ deg, int m, int* __restrict__ sums) {
    __shared__ int sm[256];
    int t = threadIdx.x;
    int base = blockIdx.x * 2048 + t * 8;
    int s = 0;
#pragma unroll
    for (int i = 0; i < 8; ++i) {
        int idx = base + i;
        if (idx < m) s += deg[idx];
    }
    sm[t] = s;
    __syncthreads();
    for (int off = 128; off > 0; off >>= 1) {
        if (t < off) sm[t] += sm[t + off];
        __syncthreads();
    }
    if (t == 0) sums[blockIdx.x] = sm[0];
}

__global__ void k_scan_offsets(int* __restrict__ sums, int nb, int* __restrict__ rp_last) {
    if (threadIdx.x == 0 && blockIdx.x == 0) {
        int run = 0;
        for (int i = 0; i < nb; ++i) { int t = sums[i]; sums[i] = run; run += t; }
        *rp_last = run;
    }
}

__global__ void k_scan_apply(const int* __restrict__ deg, int m, const int* __restrict__ sums,
                             int* __restrict__ rp, int* __restrict__ cur) {
    __shared__ int sm[256];
    int t = threadIdx.x;
    int base = blockIdx.x * 2048 + t * 8;
    int v[8];
    int s = 0;
#pragma unroll
    for (int i = 0; i < 8; ++i) {
        int idx = base + i;
        v[i] = (idx < m) ? deg[idx] : 0;
        s += v[i];
    }
    sm[t] = s;
    __syncthreads();
    for (int off = 1; off < 256; off <<= 1) {
        int add = (t >= off) ? sm[t - off] : 0;
        __syncthreads();
        sm[t] += add;
        __syncthreads();
    }
    int run = sums[blockIdx.x] + sm[t] - s;
#pragma unroll
    for (int i = 0; i < 8; ++i) {
        int idx = base + i;
        if (idx < m) { rp[idx] = run; cur[idx] = run; run += v[i]; }
    }
}

__global__ void k_scatter(const int* __restrict__ dst, const int* __restrict__ src, int E,
                          int* __restrict__ cur, int* __restrict__ out_src,
                          int* __restrict__ out_eid) {
    int e = blockIdx.x * blockDim.x + threadIdx.x;
    if (e >= E) return;
    int d = dst[e];
    int slot = atomicAdd(&cur[d], 1);
    out_src[slot] = src[e];
    if (out_eid) out_eid[slot] = e;
}

// -------------------- user routing: l2norm(pref) + 3 fused iterations ------
// wave per user; lane = g*16+l, group g handles edges j0+g, j0+g+4, ...;
// lane l covers dims 4l..4l+3. Items are frozen during routing and users are
// independent, so all 3 iterations run in one kernel, no global sync.
__global__ __launch_bounds__(256) void k_refine_user3(const float* __restrict__ P,
                                                      float* __restrict__ x,
                                                      const int* __restrict__ rp,
                                                      const int* __restrict__ srcs, int NU) {
    int u = (int)((blockIdx.x * blockDim.x + threadIdx.x) >> 6);
    int lane = threadIdx.x & 63;
    int g = lane >> 4, l = lane & 15;
    if (u >= NU) return;

    float4 xd = *(const float4*)&P[(size_t)u * 64 + l * 4];
    {   // l2norm(pref)
        float ss = xd.x * xd.x + xd.y * xd.y + xd.z * xd.z + xd.w * xd.w;
        ss = group16_sum(ss);
        float sc = 1.f / fmaxf(sqrtf(ss), 1e-12f);
        xd.x *= sc; xd.y *= sc; xd.z *= sc; xd.w *= sc;
    }
    const int j0 = rp[u], j1 = rp[u + 1];

#pragma unroll 1
    for (int it = 0; it < 3; ++it) {
        float s = 0.f;
        float4 acc = {0.f, 0.f, 0.f, 0.f};
        int j = j0 + g;
        bool valid = j < j1;
        float4 xs = {0.f, 0.f, 0.f, 0.f};
        if (valid) xs = *(const float4*)&x[(size_t)srcs[j] * 64 + l * 4];
        while (valid) {
            int jn = j + 4;
            bool vn = jn < j1;
            float4 xsn = {0.f, 0.f, 0.f, 0.f};
            if (vn) xsn = *(const float4*)&x[(size_t)srcs[jn] * 64 + l * 4];  // prefetch
            float d = xd.x * xs.x + xd.y * xs.y + xd.z * xs.z + xd.w * xs.w;
            d = group16_sum(d);
            float e = __expf(d);
            s += e;
            acc.x = fmaf(e, xs.x, acc.x); acc.y = fmaf(e, xs.y, acc.y);
            acc.z = fmaf(e, xs.z, acc.z); acc.w = fmaf(e, xs.w, acc.w);
            j = jn; xs = xsn; valid = vn;
        }
        // combine the 4 edge groups
        s += __shfl_xor(s, 16, 64); s += __shfl_xor(s, 32, 64);
        acc.x += __shfl_xor(acc.x, 16, 64); acc.x += __shfl_xor(acc.x, 32, 64);
        acc.y += __shfl_xor(acc.y, 16, 64); acc.y += __shfl_xor(acc.y, 32, 64);
        acc.z += __shfl_xor(acc.z, 16, 64); acc.z += __shfl_xor(acc.z, 32, 64);
        acc.w += __shfl_xor(acc.w, 16, 64); acc.w += __shfl_xor(acc.w, 32, 64);
        float inv = 1.f / (s + 1e-16f);
        float4 v;
        v.x = xd.x + acc.x * inv; v.y = xd.y + acc.y * inv;
        v.z = xd.z + acc.z * inv; v.w = xd.w + acc.w * inv;
        float ss = v.x * v.x + v.y * v.y + v.z * v.z + v.w * v.w;
        ss = group16_sum(ss);
        float sc = 1.f / fmaxf(sqrtf(ss), 1e-12f);
        xd.x = v.x * sc; xd.y = v.y * sc; xd.z = v.z * sc; xd.w = v.w * sc;
    }
    if (g == 0) *(float4*)&x[(size_t)u * 64 + l * 4] = xd;
}

// -------------------- final refine over full adj --------------------
__global__ __launch_bounds__(256) void k_refine_final(const float* __restrict__ x,
                                                      const int* __restrict__ rp,
                                                      const int* __restrict__ srcs,
                                                      const int* __restrict__ eids, int n,
                                                      float* __restrict__ out,
                                                      float* __restrict__ alpha,
                                                      float* __restrict__ sinv) {
    int d = (int)((blockIdx.x * blockDim.x + threadIdx.x) >> 6);
    int lane = threadIdx.x & 63;
    int g = lane >> 4, l = lane & 15;
    if (d >= n) return;

    float4 xd = *(const float4*)&x[(size_t)d * 64 + l * 4];
    const int j0 = rp[d], j1 = rp[d + 1];

    float s = 0.f;
    float4 acc = {0.f, 0.f, 0.f, 0.f};
    int j = j0 + g;
    bool valid = j < j1;
    float4 xs = {0.f, 0.f, 0.f, 0.f};
    if (valid) xs = *(const float4*)&x[(size_t)srcs[j] * 64 + l * 4];
    while (valid) {
        int jn = j + 4;
        bool vn = jn < j1;
        float4 xsn = {0.f, 0.f, 0.f, 0.f};
        if (vn) xsn = *(const float4*)&x[(size_t)srcs[jn] * 64 + l * 4];  // prefetch
        float dt = xd.x * xs.x + xd.y * xs.y + xd.z * xs.z + xd.w * xs.w;
        dt = group16_sum(dt);
        float e = __expf(dt);
        s += e;
        acc.x = fmaf(e, xs.x, acc.x); acc.y = fmaf(e, xs.y, acc.y);
        acc.z = fmaf(e, xs.z, acc.z); acc.w = fmaf(e, xs.w, acc.w);
        if (l == 0) alpha[eids[j]] = e;  // unscaled; scaled by k_alpha_scale
        j = jn; xs = xsn; valid = vn;
    }
    s += __shfl_xor(s, 16, 64); s += __shfl_xor(s, 32, 64);
    acc.x += __shfl_xor(acc.x, 16, 64); acc.x += __shfl_xor(acc.x, 32, 64);
    acc.y += __shfl_xor(acc.y, 16, 64); acc.y += __shfl_xor(acc.y, 32, 64);
    acc.z += __shfl_xor(acc.z, 16, 64); acc.z += __shfl_xor(acc.z, 32, 64);
    acc.w += __shfl_xor(acc.w, 16, 64); acc.w += __shfl_xor(acc.w, 32, 64);
    float inv = 1.f / (s + 1e-16f);
    if (lane == 0) sinv[d] = inv;
    if (g == 0) {
        float4 xh;
        xh.x = acc.x * inv; xh.y = acc.y * inv; xh.z = acc.z * inv; xh.w = acc.w * inv;
        xh.x = xh.x >= 0.f ? xh.x : 0.01f * xh.x;
        xh.y = xh.y >= 0.f ? xh.y : 0.01f * xh.y;
        xh.z = xh.z >= 0.f ? xh.z : 0.01f * xh.z;
        xh.w = xh.w >= 0.f ? xh.w : 0.01f * xh.w;
        float4 o;
        o.x = xd.x + xh.x; o.y = xd.y + xh.y; o.z = xd.z + xh.z; o.w = xd.w + xh.w;
        *(float4*)&out[(size_t)d * 64 + l * 4] = o;
    }
}

__global__ void k_alpha_scale(float* __restrict__ alpha, const int* __restrict__ adj_dst,
                              const float* __restrict__ sinv, int E) {
    int e = blockIdx.x * blockDim.x + threadIdx.x;
    if (e < E) alpha[e] *= sinv[adj_dst[e]];
}

// -------------------- orchestration --------------------
extern "C" void kernel_launch(void* const* d_in, const int* in_sizes, int n_in,
                              void* d_out, int out_size, void* d_ws, size_t ws_size,
                              hipStream_t stream) {
    const float* features = (const float*)d_in[0];
    const float* mlp_w    = (const float*)d_in[1];
    const float* mlp_b    = (const float*)d_in[2];
    const float* pref     = (const float*)d_in[3];
    const int*   adj      = (const int*)d_in[4];
    const int*   adj_u    = (const int*)d_in[5];

    const int DC = in_sizes[2];        // 64
    const int DF = in_sizes[1] / DC;   // 2048
    const int NI = in_sizes[0] / DF;   // 30000
    const int NU = in_sizes[3] / DC;   // 50000
    const int E2 = in_sizes[4] / 2;    // 2,000,000
    const int EU = in_sizes[5] / 2;    // 1,000,000
    const int n  = NU + NI;            // 80000

    char* w = (char*)d_ws;
    float* x      = (float*)w; w += (size_t)n * 64 * 4;
    int* csr_su   = (int*)w;   w += (size_t)EU * 4;
    int* csr_sf   = (int*)w;   w += (size_t)E2 * 4;
    int* csr_ef   = (int*)w;   w += (size_t)E2 * 4;
    int* rp_u     = (int*)w;   w += (size_t)(NU + 1) * 4;
    int* rp_f     = (int*)w;   w += (size_t)(n + 1) * 4;
    int* cur_u    = (int*)w;   w += (size_t)NU * 4;
    int* cur_f    = (int*)w;   w += (size_t)n * 4;
    int* deg_u    = (int*)w;   w += (size_t)NU * 4;
    int* deg_f    = (int*)w;   w += (size_t)n * 4;
    int* sums     = (int*)w;   w += 64 * 4;
    float* sinv   = (float*)w; w += (size_t)n * 4;

    hipMemsetAsync(deg_u, 0, (size_t)NU * 4, stream);
    hipMemsetAsync(deg_f, 0, (size_t)n * 4, stream);

    // item features: GEMM + leaky + l2norm -> x[NU..n)
    k_gemm<<<(NI + 63) / 64, 256, 0, stream>>>(features, mlp_w, mlp_b, x, NI, DF, NU);

    // degree histograms
    k_hist<<<(EU + 255) / 256, 256, 0, stream>>>(adj_u, EU, deg_u);
    k_hist<<<(E2 + 255) / 256, 256, 0, stream>>>(adj, E2, deg_f);

    // CSR for adj_user
    int nb_u = (NU + 2047) / 2048;
    k_scan_sums<<<nb_u, 256, 0, stream>>>(deg_u, NU, sums);
    k_scan_offsets<<<1, 64, 0, stream>>>(sums, nb_u, rp_u + NU);
    k_scan_apply<<<nb_u, 256, 0, stream>>>(deg_u, NU, sums, rp_u, cur_u);
    k_scatter<<<(EU + 255) / 256, 256, 0, stream>>>(adj_u, adj_u + EU, EU, cur_u, csr_su, nullptr);

    // CSR for full adj
    int nb_f = (n + 2047) / 2048;
    k_scan_sums<<<nb_f, 256, 0, stream>>>(deg_f, n, sums);
    k_scan_offsets<<<1, 64, 0, stream>>>(sums, nb_f, rp_f + n);
    k_scan_apply<<<nb_f, 256, 0, stream>>>(deg_f, n, sums, rp_f, cur_f);
    k_scatter<<<(E2 + 255) / 256, 256, 0, stream>>>(adj, adj + E2, E2, cur_f, csr_sf, csr_ef);

    // pref l2norm + 3 routing iterations, fused (users independent, items frozen)
    k_refine_user3<<<(NU + 3) / 4, 256, 0, stream>>>(pref, x, rp_u, csr_su, NU);

    // final refine + outputs
    float* out   = (float*)d_out;
    float* alpha = out + (size_t)n * 64;
    k_refine_final<<<(n + 3) / 4, 256, 0, stream>>>(x, rp_f, csr_sf, csr_ef, n, out, alpha, sinv);
    k_alpha_scale<<<(E2 + 255) / 256, 256, 0, stream>>>(alpha, adj, sinv, E2);
}

// Round 5
// 921.516 us; speedup vs baseline: 1.7437x; 1.1268x over previous
//
#include <hip/hip_runtime.h>
#include <hip/hip_bf16.h>

// -------------------- helpers --------------------

__device__ __forceinline__ float group16_sum(float v) {
    v += __shfl_xor(v, 1, 64);
    v += __shfl_xor(v, 2, 64);
    v += __shfl_xor(v, 4, 64);
    v += __shfl_xor(v, 8, 64);
    return v;
}

// -------------------- GEMM + leaky + l2norm --------------------
// features[NI,DF] @ W[DF,64] + b -> leaky_relu -> l2norm rows -> x[NU+i]
__global__ __launch_bounds__(256) void k_gemm(const float* __restrict__ A,
                                              const float* __restrict__ W,
                                              const float* __restrict__ Bb,
                                              float* __restrict__ x,
                                              int NI, int DF, int NU) {
    __shared__ float Ws[32][64];
    __shared__ float As[64][36];  // pad 32->36: conflict-free b128 reads
    const int tid = threadIdx.x;
    const int tc = tid & 15, tr = tid >> 4;
    const int row0 = blockIdx.x * 64;
    const int c0 = tc * 4;

    float acc[4][4];
#pragma unroll
    for (int r = 0; r < 4; ++r)
#pragma unroll
        for (int c = 0; c < 4; ++c) acc[r][c] = 0.f;

    for (int k0 = 0; k0 < DF; k0 += 32) {
        __syncthreads();
#pragma unroll
        for (int p = 0; p < 2; ++p) {
            int idx = p * 256 + tid;
            int r = idx >> 4, c4 = (idx & 15) * 4;
            *(float4*)&Ws[r][c4] = *(const float4*)&W[(size_t)(k0 + r) * 64 + c4];
        }
#pragma unroll
        for (int p = 0; p < 2; ++p) {
            int lin = p * 256 + tid;
            int r = lin >> 3, c4 = (lin & 7) * 4;
            int gr = row0 + r;
            if (gr >= NI) gr = NI - 1;
            *(float4*)&As[r][c4] = *(const float4*)&A[(size_t)gr * DF + k0 + c4];
        }
        __syncthreads();
#pragma unroll
        for (int kk = 0; kk < 32; kk += 4) {
            float b[4][4];
#pragma unroll
            for (int i = 0; i < 4; ++i)
                *(float4*)b[i] = *(const float4*)&Ws[kk + i][c0];
#pragma unroll
            for (int rr = 0; rr < 4; ++rr) {
                float a[4];
                *(float4*)a = *(const float4*)&As[rr * 16 + tr][kk];
#pragma unroll
                for (int i = 0; i < 4; ++i)
#pragma unroll
                    for (int c = 0; c < 4; ++c)
                        acc[rr][c] = fmaf(a[i], b[i][c], acc[rr][c]);
            }
        }
    }

    float bias[4];
    *(float4*)bias = *(const float4*)&Bb[c0];

#pragma unroll
    for (int rr = 0; rr < 4; ++rr) {
        int gr = row0 + rr * 16 + tr;
        float v[4];
#pragma unroll
        for (int c = 0; c < 4; ++c) {
            float t = acc[rr][c] + bias[c];
            v[c] = t >= 0.f ? t : 0.01f * t;  // leaky_relu
        }
        float ss = v[0] * v[0] + v[1] * v[1] + v[2] * v[2] + v[3] * v[3];
#pragma unroll
        for (int off = 1; off < 16; off <<= 1) ss += __shfl_xor(ss, off, 64);
        float scale = 1.f / fmaxf(sqrtf(ss), 1e-12f);
        if (gr < NI) {
            float4 o;
            o.x = v[0] * scale; o.y = v[1] * scale; o.z = v[2] * scale; o.w = v[3] * scale;
            *(float4*)&x[(size_t)(NU + gr) * 64 + c0] = o;
        }
    }
}

// -------------------- CSR build (structure-aware) --------------------
// adj = [[u,it],[it,u]]: user-dst half of full graph == adj_user (eid=e),
// item-dst half is the SAME 1M edges grouped by item (eid=EU+e). One pass
// builds both CSRs; (src,eid) packed in int2 -> single 8B random store.

__global__ void k_hist2(const int* __restrict__ u, const int* __restrict__ it, int E,
                        int* __restrict__ deg_u, int* __restrict__ deg_i, int NU) {
    int e = blockIdx.x * blockDim.x + threadIdx.x;
    if (e >= E) return;
    atomicAdd(&deg_u[u[e]], 1);
    atomicAdd(&deg_i[it[e] - NU], 1);
}

__global__ void k_scan_sums(const int* __restrict__ deg, int m, int* __restrict__ sums) {
    __shared__ int sm[256];
    int t = threadIdx.x;
    int base = blockIdx.x * 2048 + t * 8;
    int s = 0;
#pragma unroll
    for (int i = 0; i < 8; ++i) {
        int idx = base + i;
        if (idx < m) s += deg[idx];
    }
    sm[t] = s;
    __syncthreads();
    for (int off = 128; off > 0; off >>= 1) {
        if (t < off) sm[t] += sm[t + off];
        __syncthreads();
    }
    if (t == 0) sums[blockIdx.x] = sm[0];
}

__global__ void k_scan_offsets(int* __restrict__ sums, int nb, int* __restrict__ rp_last) {
    if (threadIdx.x == 0 && blockIdx.x == 0) {
        int run = 0;
        for (int i = 0; i < nb; ++i) { int t = sums[i]; sums[i] = run; run += t; }
        *rp_last = run;
    }
}

__global__ void k_scan_apply(const int* __restrict__ deg, int m, const int* __restrict__ sums,
                             int* __restrict__ rp, int* __restrict__ cur) {
    __shared__ int sm[256];
    int t = threadIdx.x;
    int base = blockIdx.x * 2048 + t * 8;
    int v[8];
    int s = 0;
#pragma unroll
    for (int i = 0; i < 8; ++i) {
        int idx = base + i;
        v[i] = (idx < m) ? deg[idx] : 0;
        s += v[i];
    }
    sm[t] = s;
    __syncthreads();
    for (int off = 1; off < 256; off <<= 1) {
        int add = (t >= off) ? sm[t - off] : 0;
        __syncthreads();
        sm[t] += add;
        __syncthreads();
    }
    int run = sums[blockIdx.x] + sm[t] - s;
#pragma unroll
    for (int i = 0; i < 8; ++i) {
        int idx = base + i;
        if (idx < m) { rp[idx] = run; cur[idx] = run; run += v[i]; }
    }
}

__global__ void k_scatter2(const int* __restrict__ u, const int* __restrict__ it, int E,
                           int* __restrict__ cur_u, int* __restrict__ cur_i,
                           int2* __restrict__ pair_u, int2* __restrict__ pair_i,
                           int NU, int EU) {
    int e = blockIdx.x * blockDim.x + threadIdx.x;
    if (e >= E) return;
    int uu = u[e], ii = it[e];
    int su = atomicAdd(&cur_u[uu], 1);
    pair_u[su] = make_int2(ii, e);
    int si = atomicAdd(&cur_i[ii - NU], 1);
    pair_i[si] = make_int2(uu, EU + e);
}

// -------------------- user routing: l2norm(pref) + 3 fused iterations ------
__global__ __launch_bounds__(256) void k_refine_user3(const float* __restrict__ P,
                                                      float* __restrict__ x,
                                                      const int* __restrict__ rp,
                                                      const int2* __restrict__ pairs, int NU) {
    int u = (int)((blockIdx.x * blockDim.x + threadIdx.x) >> 6);
    int lane = threadIdx.x & 63;
    int g = lane >> 4, l = lane & 15;
    if (u >= NU) return;

    float4 xd = *(const float4*)&P[(size_t)u * 64 + l * 4];
    {   // l2norm(pref)
        float ss = xd.x * xd.x + xd.y * xd.y + xd.z * xd.z + xd.w * xd.w;
        ss = group16_sum(ss);
        float sc = 1.f / fmaxf(sqrtf(ss), 1e-12f);
        xd.x *= sc; xd.y *= sc; xd.z *= sc; xd.w *= sc;
    }
    const int j0 = rp[u], j1 = rp[u + 1];

#pragma unroll 1
    for (int it = 0; it < 3; ++it) {
        float s = 0.f;
        float4 acc = {0.f, 0.f, 0.f, 0.f};
        int j = j0 + g;
        bool valid = j < j1;
        float4 xs = {0.f, 0.f, 0.f, 0.f};
        if (valid) xs = *(const float4*)&x[(size_t)pairs[j].x * 64 + l * 4];
        while (valid) {
            int jn = j + 4;
            bool vn = jn < j1;
            float4 xsn = {0.f, 0.f, 0.f, 0.f};
            if (vn) xsn = *(const float4*)&x[(size_t)pairs[jn].x * 64 + l * 4];  // prefetch
            float d = xd.x * xs.x + xd.y * xs.y + xd.z * xs.z + xd.w * xs.w;
            d = group16_sum(d);
            float e = __expf(d);
            s += e;
            acc.x = fmaf(e, xs.x, acc.x); acc.y = fmaf(e, xs.y, acc.y);
            acc.z = fmaf(e, xs.z, acc.z); acc.w = fmaf(e, xs.w, acc.w);
            j = jn; xs = xsn; valid = vn;
        }
        s += __shfl_xor(s, 16, 64); s += __shfl_xor(s, 32, 64);
        acc.x += __shfl_xor(acc.x, 16, 64); acc.x += __shfl_xor(acc.x, 32, 64);
        acc.y += __shfl_xor(acc.y, 16, 64); acc.y += __shfl_xor(acc.y, 32, 64);
        acc.z += __shfl_xor(acc.z, 16, 64); acc.z += __shfl_xor(acc.z, 32, 64);
        acc.w += __shfl_xor(acc.w, 16, 64); acc.w += __shfl_xor(acc.w, 32, 64);
        float inv = 1.f / (s + 1e-16f);
        float4 v;
        v.x = xd.x + acc.x * inv; v.y = xd.y + acc.y * inv;
        v.z = xd.z + acc.z * inv; v.w = xd.w + acc.w * inv;
        float ss = v.x * v.x + v.y * v.y + v.z * v.z + v.w * v.w;
        ss = group16_sum(ss);
        float sc = 1.f / fmaxf(sqrtf(ss), 1e-12f);
        xd.x = v.x * sc; xd.y = v.y * sc; xd.z = v.z * sc; xd.w = v.w * sc;
    }
    if (g == 0) *(float4*)&x[(size_t)u * 64 + l * 4] = xd;
}

// -------------------- final refine over full adj --------------------
__global__ __launch_bounds__(256) void k_refine_final(const float* __restrict__ x,
                                                      const int* __restrict__ rp_u,
                                                      const int2* __restrict__ pu,
                                                      const int* __restrict__ rp_i,
                                                      const int2* __restrict__ pi,
                                                      int NU, int n,
                                                      float* __restrict__ out,
                                                      float* __restrict__ alpha,
                                                      float* __restrict__ sinv) {
    int d = (int)((blockIdx.x * blockDim.x + threadIdx.x) >> 6);
    int lane = threadIdx.x & 63;
    int g = lane >> 4, l = lane & 15;
    if (d >= n) return;

    int j0, j1;
    const int2* pp;
    if (d < NU) { j0 = rp_u[d]; j1 = rp_u[d + 1]; pp = pu; }
    else        { j0 = rp_i[d - NU]; j1 = rp_i[d - NU + 1]; pp = pi; }

    float4 xd = *(const float4*)&x[(size_t)d * 64 + l * 4];

    float s = 0.f;
    float4 acc = {0.f, 0.f, 0.f, 0.f};
    int j = j0 + g;
    bool valid = j < j1;
    int2 pr = valid ? pp[j] : make_int2(0, 0);
    float4 xs = {0.f, 0.f, 0.f, 0.f};
    if (valid) xs = *(const float4*)&x[(size_t)pr.x * 64 + l * 4];
    while (valid) {
        int jn = j + 4;
        bool vn = jn < j1;
        int2 prn = vn ? pp[jn] : make_int2(0, 0);
        float4 xsn = {0.f, 0.f, 0.f, 0.f};
        if (vn) xsn = *(const float4*)&x[(size_t)prn.x * 64 + l * 4];  // prefetch
        float dt = xd.x * xs.x + xd.y * xs.y + xd.z * xs.z + xd.w * xs.w;
        dt = group16_sum(dt);
        float e = __expf(dt);
        s += e;
        acc.x = fmaf(e, xs.x, acc.x); acc.y = fmaf(e, xs.y, acc.y);
        acc.z = fmaf(e, xs.z, acc.z); acc.w = fmaf(e, xs.w, acc.w);
        if (l == 0) alpha[pr.y] = e;  // unscaled; scaled by k_alpha_scale
        j = jn; pr = prn; xs = xsn; valid = vn;
    }
    s += __shfl_xor(s, 16, 64); s += __shfl_xor(s, 32, 64);
    acc.x += __shfl_xor(acc.x, 16, 64); acc.x += __shfl_xor(acc.x, 32, 64);
    acc.y += __shfl_xor(acc.y, 16, 64); acc.y += __shfl_xor(acc.y, 32, 64);
    acc.z += __shfl_xor(acc.z, 16, 64); acc.z += __shfl_xor(acc.z, 32, 64);
    acc.w += __shfl_xor(acc.w, 16, 64); acc.w += __shfl_xor(acc.w, 32, 64);
    float inv = 1.f / (s + 1e-16f);
    if (lane == 0) sinv[d] = inv;
    if (g == 0) {
        float4 xh;
        xh.x = acc.x * inv; xh.y = acc.y * inv; xh.z = acc.z * inv; xh.w = acc.w * inv;
        xh.x = xh.x >= 0.f ? xh.x : 0.01f * xh.x;
        xh.y = xh.y >= 0.f ? xh.y : 0.01f * xh.y;
        xh.z = xh.z >= 0.f ? xh.z : 0.01f * xh.z;
        xh.w = xh.w >= 0.f ? xh.w : 0.01f * xh.w;
        float4 o;
        o.x = xd.x + xh.x; o.y = xd.y + xh.y; o.z = xd.z + xh.z; o.w = xd.w + xh.w;
        *(float4*)&out[(size_t)d * 64 + l * 4] = o;
    }
}

__global__ void k_alpha_scale(float* __restrict__ alpha, const int* __restrict__ adj_dst,
                              const float* __restrict__ sinv, int E) {
    int e = blockIdx.x * blockDim.x + threadIdx.x;
    if (e < E) alpha[e] *= sinv[adj_dst[e]];
}

// -------------------- orchestration --------------------
extern "C" void kernel_launch(void* const* d_in, const int* in_sizes, int n_in,
                              void* d_out, int out_size, void* d_ws, size_t ws_size,
                              hipStream_t stream) {
    const float* features = (const float*)d_in[0];
    const float* mlp_w    = (const float*)d_in[1];
    const float* mlp_b    = (const float*)d_in[2];
    const float* pref     = (const float*)d_in[3];
    const int*   adj      = (const int*)d_in[4];
    const int*   adj_u    = (const int*)d_in[5];

    const int DC = in_sizes[2];        // 64
    const int DF = in_sizes[1] / DC;   // 2048
    const int NI = in_sizes[0] / DF;   // 30000
    const int NU = in_sizes[3] / DC;   // 50000
    const int E2 = in_sizes[4] / 2;    // 2,000,000
    const int EU = in_sizes[5] / 2;    // 1,000,000
    const int n  = NU + NI;            // 80000

    // workspace layout (8B-aligned arrays first)
    char* w = (char*)d_ws;
    int2* pair_u  = (int2*)w;  w += (size_t)EU * 8;
    int2* pair_i  = (int2*)w;  w += (size_t)EU * 8;
    float* x      = (float*)w; w += (size_t)n * 64 * 4;
    int* rp_u     = (int*)w;   w += (size_t)(NU + 1) * 4;
    int* rp_i     = (int*)w;   w += (size_t)(NI + 1) * 4;
    int* cur_u    = (int*)w;   w += (size_t)NU * 4;
    int* cur_i    = (int*)w;   w += (size_t)NI * 4;
    int* deg_u    = (int*)w;   w += (size_t)NU * 4;
    int* deg_i    = (int*)w;   w += (size_t)NI * 4;
    int* sums     = (int*)w;   w += 64 * 4;
    float* sinv   = (float*)w; w += (size_t)n * 4;

    hipMemsetAsync(deg_u, 0, (size_t)NU * 4, stream);
    hipMemsetAsync(deg_i, 0, (size_t)NI * 4, stream);

    // item features: GEMM + leaky + l2norm -> x[NU..n)
    k_gemm<<<(NI + 63) / 64, 256, 0, stream>>>(features, mlp_w, mlp_b, x, NI, DF, NU);

    // one histogram pass builds both degree arrays
    k_hist2<<<(EU + 255) / 256, 256, 0, stream>>>(adj_u, adj_u + EU, EU, deg_u, deg_i, NU);

    // scans
    int nb_u = (NU + 2047) / 2048;
    k_scan_sums<<<nb_u, 256, 0, stream>>>(deg_u, NU, sums);
    k_scan_offsets<<<1, 64, 0, stream>>>(sums, nb_u, rp_u + NU);
    k_scan_apply<<<nb_u, 256, 0, stream>>>(deg_u, NU, sums, rp_u, cur_u);

    int nb_i = (NI + 2047) / 2048;
    k_scan_sums<<<nb_i, 256, 0, stream>>>(deg_i, NI, sums);
    k_scan_offsets<<<1, 64, 0, stream>>>(sums, nb_i, rp_i + NI);
    k_scan_apply<<<nb_i, 256, 0, stream>>>(deg_i, NI, sums, rp_i, cur_i);

    // one scatter pass builds both CSRs ((src,eid) packed int2)
    k_scatter2<<<(EU + 255) / 256, 256, 0, stream>>>(adj_u, adj_u + EU, EU, cur_u, cur_i,
                                                     pair_u, pair_i, NU, EU);

    // pref l2norm + 3 routing iterations, fused
    k_refine_user3<<<(NU + 3) / 4, 256, 0, stream>>>(pref, x, rp_u, pair_u, NU);

    // final refine + outputs
    float* out   = (float*)d_out;
    float* alpha = out + (size_t)n * 64;
    k_refine_final<<<(n + 3) / 4, 256, 0, stream>>>(x, rp_u, pair_u, rp_i, pair_i, NU, n,
                                                    out, alpha, sinv);
    k_alpha_scale<<<(E2 + 255) / 256, 256, 0, stream>>>(alpha, adj, sinv, E2);
}

// Round 7
// 903.473 us; speedup vs baseline: 1.7785x; 1.0200x over previous
//
#include <hip/hip_runtime.h>
#include <hip/hip_bf16.h>

// -------------------- helpers --------------------

__device__ __forceinline__ float group16_sum(float v) {
    v += __shfl_xor(v, 1, 64);
    v += __shfl_xor(v, 2, 64);
    v += __shfl_xor(v, 4, 64);
    v += __shfl_xor(v, 8, 64);
    return v;
}

// -------------------- GEMM + leaky + l2norm --------------------
// features[NI,DF] @ W[DF,64] + b -> leaky_relu -> l2norm rows -> x[NU+i]
__global__ __launch_bounds__(256) void k_gemm(const float* __restrict__ A,
                                              const float* __restrict__ W,
                                              const float* __restrict__ Bb,
                                              float* __restrict__ x,
                                              int NI, int DF, int NU) {
    __shared__ float Ws[32][64];
    __shared__ float As[64][36];  // pad 32->36: conflict-free b128 reads
    const int tid = threadIdx.x;
    const int tc = tid & 15, tr = tid >> 4;
    const int row0 = blockIdx.x * 64;
    const int c0 = tc * 4;

    float acc[4][4];
#pragma unroll
    for (int r = 0; r < 4; ++r)
#pragma unroll
        for (int c = 0; c < 4; ++c) acc[r][c] = 0.f;

    for (int k0 = 0; k0 < DF; k0 += 32) {
        __syncthreads();
#pragma unroll
        for (int p = 0; p < 2; ++p) {
            int idx = p * 256 + tid;
            int r = idx >> 4, c4 = (idx & 15) * 4;
            *(float4*)&Ws[r][c4] = *(const float4*)&W[(size_t)(k0 + r) * 64 + c4];
        }
#pragma unroll
        for (int p = 0; p < 2; ++p) {
            int lin = p * 256 + tid;
            int r = lin >> 3, c4 = (lin & 7) * 4;
            int gr = row0 + r;
            if (gr >= NI) gr = NI - 1;
            *(float4*)&As[r][c4] = *(const float4*)&A[(size_t)gr * DF + k0 + c4];
        }
        __syncthreads();
#pragma unroll
        for (int kk = 0; kk < 32; kk += 4) {
            float b[4][4];
#pragma unroll
            for (int i = 0; i < 4; ++i)
                *(float4*)b[i] = *(const float4*)&Ws[kk + i][c0];
#pragma unroll
            for (int rr = 0; rr < 4; ++rr) {
                float a[4];
                *(float4*)a = *(const float4*)&As[rr * 16 + tr][kk];
#pragma unroll
                for (int i = 0; i < 4; ++i)
#pragma unroll
                    for (int c = 0; c < 4; ++c)
                        acc[rr][c] = fmaf(a[i], b[i][c], acc[rr][c]);
            }
        }
    }

    float bias[4];
    *(float4*)bias = *(const float4*)&Bb[c0];

#pragma unroll
    for (int rr = 0; rr < 4; ++rr) {
        int gr = row0 + rr * 16 + tr;
        float v[4];
#pragma unroll
        for (int c = 0; c < 4; ++c) {
            float t = acc[rr][c] + bias[c];
            v[c] = t >= 0.f ? t : 0.01f * t;  // leaky_relu
        }
        float ss = v[0] * v[0] + v[1] * v[1] + v[2] * v[2] + v[3] * v[3];
#pragma unroll
        for (int off = 1; off < 16; off <<= 1) ss += __shfl_xor(ss, off, 64);
        float scale = 1.f / fmaxf(sqrtf(ss), 1e-12f);
        if (gr < NI) {
            float4 o;
            o.x = v[0] * scale; o.y = v[1] * scale; o.z = v[2] * scale; o.w = v[3] * scale;
            *(float4*)&x[(size_t)(NU + gr) * 64 + c0] = o;
        }
    }
}

// -------------------- CSR build (structure-aware) --------------------
// adj = [[u,it],[it,u]]: user-dst half of full graph == adj_user (eid=e),
// item-dst half is the SAME 1M edges grouped by item (eid=EU+e). One pass
// builds both CSRs; (src,eid) packed in int2 -> single 8B random store.
// 4 edges/thread: 8 independent atomic chains per thread to cover L2
// atomic-return latency (round-5 profile: VALUBusy 0.2%, HBM 9% -> TLP-starved).

__global__ void k_hist2(const int* __restrict__ u, const int* __restrict__ it, int E,
                        int* __restrict__ deg_u, int* __restrict__ deg_i, int NU) {
    int e0 = (blockIdx.x * blockDim.x + threadIdx.x) * 4;
    if (e0 + 3 < E) {
        int4 uu = *(const int4*)&u[e0];
        int4 ii = *(const int4*)&it[e0];
        atomicAdd(&deg_u[uu.x], 1); atomicAdd(&deg_u[uu.y], 1);
        atomicAdd(&deg_u[uu.z], 1); atomicAdd(&deg_u[uu.w], 1);
        atomicAdd(&deg_i[ii.x - NU], 1); atomicAdd(&deg_i[ii.y - NU], 1);
        atomicAdd(&deg_i[ii.z - NU], 1); atomicAdd(&deg_i[ii.w - NU], 1);
    } else {
        for (int e = e0; e < E; ++e) {
            atomicAdd(&deg_u[u[e]], 1);
            atomicAdd(&deg_i[it[e] - NU], 1);
        }
    }
}

__global__ void k_scan_sums(const int* __restrict__ deg, int m, int* __restrict__ sums) {
    __shared__ int sm[256];
    int t = threadIdx.x;
    int base = blockIdx.x * 2048 + t * 8;
    int s = 0;
#pragma unroll
    for (int i = 0; i < 8; ++i) {
        int idx = base + i;
        if (idx < m) s += deg[idx];
    }
    sm[t] = s;
    __syncthreads();
    for (int off = 128; off > 0; off >>= 1) {
        if (t < off) sm[t] += sm[t + off];
        __syncthreads();
    }
    if (t == 0) sums[blockIdx.x] = sm[0];
}

__global__ void k_scan_offsets(int* __restrict__ sums, int nb, int* __restrict__ rp_last) {
    if (threadIdx.x == 0 && blockIdx.x == 0) {
        int run = 0;
        for (int i = 0; i < nb; ++i) { int t = sums[i]; sums[i] = run; run += t; }
        *rp_last = run;
    }
}

__global__ void k_scan_apply(const int* __restrict__ deg, int m, const int* __restrict__ sums,
                             int* __restrict__ rp, int* __restrict__ cur) {
    __shared__ int sm[256];
    int t = threadIdx.x;
    int base = blockIdx.x * 2048 + t * 8;
    int v[8];
    int s = 0;
#pragma unroll
    for (int i = 0; i < 8; ++i) {
        int idx = base + i;
        v[i] = (idx < m) ? deg[idx] : 0;
        s += v[i];
    }
    sm[t] = s;
    __syncthreads();
    for (int off = 1; off < 256; off <<= 1) {
        int add = (t >= off) ? sm[t - off] : 0;
        __syncthreads();
        sm[t] += add;
        __syncthreads();
    }
    int run = sums[blockIdx.x] + sm[t] - s;
#pragma unroll
    for (int i = 0; i < 8; ++i) {
        int idx = base + i;
        if (idx < m) { rp[idx] = run; cur[idx] = run; run += v[i]; }
    }
}

__global__ void k_scatter2(const int* __restrict__ u, const int* __restrict__ it, int E,
                           int* __restrict__ cur_u, int* __restrict__ cur_i,
                           int2* __restrict__ pair_u, int2* __restrict__ pair_i,
                           int NU, int EU) {
    int e0 = (blockIdx.x * blockDim.x + threadIdx.x) * 4;
    if (e0 + 3 < E) {
        int4 uu = *(const int4*)&u[e0];
        int4 ii = *(const int4*)&it[e0];
        int uarr[4] = {uu.x, uu.y, uu.z, uu.w};
        int iarr[4] = {ii.x, ii.y, ii.z, ii.w};
        int su[4], si[4];
#pragma unroll
        for (int k = 0; k < 4; ++k) su[k] = atomicAdd(&cur_u[uarr[k]], 1);
#pragma unroll
        for (int k = 0; k < 4; ++k) si[k] = atomicAdd(&cur_i[iarr[k] - NU], 1);
#pragma unroll
        for (int k = 0; k < 4; ++k) pair_u[su[k]] = make_int2(iarr[k], e0 + k);
#pragma unroll
        for (int k = 0; k < 4; ++k) pair_i[si[k]] = make_int2(uarr[k], EU + e0 + k);
    } else {
        for (int e = e0; e < E; ++e) {
            int uu = u[e], ii = it[e];
            int su = atomicAdd(&cur_u[uu], 1);
            pair_u[su] = make_int2(ii, e);
            int si = atomicAdd(&cur_i[ii - NU], 1);
            pair_i[si] = make_int2(uu, EU + e);
        }
    }
}

// -------------------- user routing: l2norm(pref) + 3 fused iterations ------
__global__ __launch_bounds__(256) void k_refine_user3(const float* __restrict__ P,
                                                      float* __restrict__ x,
                                                      const int* __restrict__ rp,
                                                      const int2* __restrict__ pairs, int NU) {
    int u = (int)((blockIdx.x * blockDim.x + threadIdx.x) >> 6);
    int lane = threadIdx.x & 63;
    int g = lane >> 4, l = lane & 15;
    if (u >= NU) return;

    float4 xd = *(const float4*)&P[(size_t)u * 64 + l * 4];
    {   // l2norm(pref)
        float ss = xd.x * xd.x + xd.y * xd.y + xd.z * xd.z + xd.w * xd.w;
        ss = group16_sum(ss);
        float sc = 1.f / fmaxf(sqrtf(ss), 1e-12f);
        xd.x *= sc; xd.y *= sc; xd.z *= sc; xd.w *= sc;
    }
    const int j0 = rp[u], j1 = rp[u + 1];

#pragma unroll 1
    for (int it = 0; it < 3; ++it) {
        float s = 0.f;
        float4 acc = {0.f, 0.f, 0.f, 0.f};
        int j = j0 + g;
        bool valid = j < j1;
        float4 xs = {0.f, 0.f, 0.f, 0.f};
        if (valid) xs = *(const float4*)&x[(size_t)pairs[j].x * 64 + l * 4];
        while (valid) {
            int jn = j + 4;
            bool vn = jn < j1;
            float4 xsn = {0.f, 0.f, 0.f, 0.f};
            if (vn) xsn = *(const float4*)&x[(size_t)pairs[jn].x * 64 + l * 4];  // prefetch
            float d = xd.x * xs.x + xd.y * xs.y + xd.z * xs.z + xd.w * xs.w;
            d = group16_sum(d);
            float e = __expf(d);
            s += e;
            acc.x = fmaf(e, xs.x, acc.x); acc.y = fmaf(e, xs.y, acc.y);
            acc.z = fmaf(e, xs.z, acc.z); acc.w = fmaf(e, xs.w, acc.w);
            j = jn; xs = xsn; valid = vn;
        }
        s += __shfl_xor(s, 16, 64); s += __shfl_xor(s, 32, 64);
        acc.x += __shfl_xor(acc.x, 16, 64); acc.x += __shfl_xor(acc.x, 32, 64);
        acc.y += __shfl_xor(acc.y, 16, 64); acc.y += __shfl_xor(acc.y, 32, 64);
        acc.z += __shfl_xor(acc.z, 16, 64); acc.z += __shfl_xor(acc.z, 32, 64);
        acc.w += __shfl_xor(acc.w, 16, 64); acc.w += __shfl_xor(acc.w, 32, 64);
        float inv = 1.f / (s + 1e-16f);
        float4 v;
        v.x = xd.x + acc.x * inv; v.y = xd.y + acc.y * inv;
        v.z = xd.z + acc.z * inv; v.w = xd.w + acc.w * inv;
        float ss = v.x * v.x + v.y * v.y + v.z * v.z + v.w * v.w;
        ss = group16_sum(ss);
        float sc = 1.f / fmaxf(sqrtf(ss), 1e-12f);
        xd.x = v.x * sc; xd.y = v.y * sc; xd.z = v.z * sc; xd.w = v.w * sc;
    }
    if (g == 0) *(float4*)&x[(size_t)u * 64 + l * 4] = xd;
}

// -------------------- final refine over full adj --------------------
__global__ __launch_bounds__(256) void k_refine_final(const float* __restrict__ x,
                                                      const int* __restrict__ rp_u,
                                                      const int2* __restrict__ pu,
                                                      const int* __restrict__ rp_i,
                                                      const int2* __restrict__ pi,
                                                      int NU, int n,
                                                      float* __restrict__ out,
                                                      float* __restrict__ alpha,
                                                      float* __restrict__ sinv) {
    int d = (int)((blockIdx.x * blockDim.x + threadIdx.x) >> 6);
    int lane = threadIdx.x & 63;
    int g = lane >> 4, l = lane & 15;
    if (d >= n) return;

    int j0, j1;
    const int2* pp;
    if (d < NU) { j0 = rp_u[d]; j1 = rp_u[d + 1]; pp = pu; }
    else        { j0 = rp_i[d - NU]; j1 = rp_i[d - NU + 1]; pp = pi; }

    float4 xd = *(const float4*)&x[(size_t)d * 64 + l * 4];

    float s = 0.f;
    float4 acc = {0.f, 0.f, 0.f, 0.f};
    int j = j0 + g;
    bool valid = j < j1;
    int2 pr = valid ? pp[j] : make_int2(0, 0);
    float4 xs = {0.f, 0.f, 0.f, 0.f};
    if (valid) xs = *(const float4*)&x[(size_t)pr.x * 64 + l * 4];
    while (valid) {
        int jn = j + 4;
        bool vn = jn < j1;
        int2 prn = vn ? pp[jn] : make_int2(0, 0);
        float4 xsn = {0.f, 0.f, 0.f, 0.f};
        if (vn) xsn = *(const float4*)&x[(size_t)prn.x * 64 + l * 4];  // prefetch
        float dt = xd.x * xs.x + xd.y * xs.y + xd.z * xs.z + xd.w * xs.w;
        dt = group16_sum(dt);
        float e = __expf(dt);
        s += e;
        acc.x = fmaf(e, xs.x, acc.x); acc.y = fmaf(e, xs.y, acc.y);
        acc.z = fmaf(e, xs.z, acc.z); acc.w = fmaf(e, xs.w, acc.w);
        if (l == 0) alpha[pr.y] = e;  // unscaled; scaled by k_alpha_scale
        j = jn; pr = prn; xs = xsn; valid = vn;
    }
    s += __shfl_xor(s, 16, 64); s += __shfl_xor(s, 32, 64);
    acc.x += __shfl_xor(acc.x, 16, 64); acc.x += __shfl_xor(acc.x, 32, 64);
    acc.y += __shfl_xor(acc.y, 16, 64); acc.y += __shfl_xor(acc.y, 32, 64);
    acc.z += __shfl_xor(acc.z, 16, 64); acc.z += __shfl_xor(acc.z, 32, 64);
    acc.w += __shfl_xor(acc.w, 16, 64); acc.w += __shfl_xor(acc.w, 32, 64);
    float inv = 1.f / (s + 1e-16f);
    if (lane == 0) sinv[d] = inv;
    if (g == 0) {
        float4 xh;
        xh.x = acc.x * inv; xh.y = acc.y * inv; xh.z = acc.z * inv; xh.w = acc.w * inv;
        xh.x = xh.x >= 0.f ? xh.x : 0.01f * xh.x;
        xh.y = xh.y >= 0.f ? xh.y : 0.01f * xh.y;
        xh.z = xh.z >= 0.f ? xh.z : 0.01f * xh.z;
        xh.w = xh.w >= 0.f ? xh.w : 0.01f * xh.w;
        float4 o;
        o.x = xd.x + xh.x; o.y = xd.y + xh.y; o.z = xd.z + xh.z; o.w = xd.w + xh.w;
        *(float4*)&out[(size_t)d * 64 + l * 4] = o;
    }
}

__global__ void k_alpha_scale(float* __restrict__ alpha, const int* __restrict__ adj_dst,
                              const float* __restrict__ sinv, int E) {
    int e = blockIdx.x * blockDim.x + threadIdx.x;
    if (e < E) alpha[e] *= sinv[adj_dst[e]];
}

// -------------------- orchestration --------------------
extern "C" void kernel_launch(void* const* d_in, const int* in_sizes, int n_in,
                              void* d_out, int out_size, void* d_ws, size_t ws_size,
                              hipStream_t stream) {
    const float* features = (const float*)d_in[0];
    const float* mlp_w    = (const float*)d_in[1];
    const float* mlp_b    = (const float*)d_in[2];
    const float* pref     = (const float*)d_in[3];
    const int*   adj      = (const int*)d_in[4];
    const int*   adj_u    = (const int*)d_in[5];

    const int DC = in_sizes[2];        // 64
    const int DF = in_sizes[1] / DC;   // 2048
    const int NI = in_sizes[0] / DF;   // 30000
    const int NU = in_sizes[3] / DC;   // 50000
    const int E2 = in_sizes[4] / 2;    // 2,000,000
    const int EU = in_sizes[5] / 2;    // 1,000,000
    const int n  = NU + NI;            // 80000

    // workspace layout (8B-aligned arrays first)
    char* w = (char*)d_ws;
    int2* pair_u  = (int2*)w;  w += (size_t)EU * 8;
    int2* pair_i  = (int2*)w;  w += (size_t)EU * 8;
    float* x      = (float*)w; w += (size_t)n * 64 * 4;
    int* rp_u     = (int*)w;   w += (size_t)(NU + 1) * 4;
    int* rp_i     = (int*)w;   w += (size_t)(NI + 1) * 4;
    int* cur_u    = (int*)w;   w += (size_t)NU * 4;
    int* cur_i    = (int*)w;   w += (size_t)NI * 4;
    int* deg_u    = (int*)w;   w += (size_t)NU * 4;
    int* deg_i    = (int*)w;   w += (size_t)NI * 4;
    int* sums     = (int*)w;   w += 64 * 4;
    float* sinv   = (float*)w; w += (size_t)n * 4;

    hipMemsetAsync(deg_u, 0, (size_t)NU * 4, stream);
    hipMemsetAsync(deg_i, 0, (size_t)NI * 4, stream);

    // item features: GEMM + leaky + l2norm -> x[NU..n)
    k_gemm<<<(NI + 63) / 64, 256, 0, stream>>>(features, mlp_w, mlp_b, x, NI, DF, NU);

    // one histogram pass builds both degree arrays (4 edges/thread)
    k_hist2<<<(EU / 4 + 255) / 256, 256, 0, stream>>>(adj_u, adj_u + EU, EU, deg_u, deg_i, NU);

    // scans
    int nb_u = (NU + 2047) / 2048;
    k_scan_sums<<<nb_u, 256, 0, stream>>>(deg_u, NU, sums);
    k_scan_offsets<<<1, 64, 0, stream>>>(sums, nb_u, rp_u + NU);
    k_scan_apply<<<nb_u, 256, 0, stream>>>(deg_u, NU, sums, rp_u, cur_u);

    int nb_i = (NI + 2047) / 2048;
    k_scan_sums<<<nb_i, 256, 0, stream>>>(deg_i, NI, sums);
    k_scan_offsets<<<1, 64, 0, stream>>>(sums, nb_i, rp_i + NI);
    k_scan_apply<<<nb_i, 256, 0, stream>>>(deg_i, NI, sums, rp_i, cur_i);

    // one scatter pass builds both CSRs ((src,eid) packed int2, 4 edges/thread)
    k_scatter2<<<(EU / 4 + 255) / 256, 256, 0, stream>>>(adj_u, adj_u + EU, EU, cur_u, cur_i,
                                                         pair_u, pair_i, NU, EU);

    // pref l2norm + 3 routing iterations, fused
    k_refine_user3<<<(NU + 3) / 4, 256, 0, stream>>>(pref, x, rp_u, pair_u, NU);

    // final refine + outputs
    float* out   = (float*)d_out;
    float* alpha = out + (size_t)n * 64;
    k_refine_final<<<(n + 3) / 4, 256, 0, stream>>>(x, rp_u, pair_u, rp_i, pair_i, NU, n,
                                                    out, alpha, sinv);
    k_alpha_scale<<<(E2 + 255) / 256, 256, 0, stream>>>(alpha, adj, sinv, E2);
}

// Round 9
// 863.074 us; speedup vs baseline: 1.8618x; 1.0468x over previous
//
#include <hip/hip_runtime.h>
#include <hip/hip_bf16.h>

// -------------------- helpers --------------------

__device__ __forceinline__ float group16_sum(float v) {
    v += __shfl_xor(v, 1, 64);
    v += __shfl_xor(v, 2, 64);
    v += __shfl_xor(v, 4, 64);
    v += __shfl_xor(v, 8, 64);
    return v;
}

// -------------------- fused GEMM + edge histogram --------------------
// blocks [0, ngemm): features[NI,DF] @ W[DF,64] + b -> leaky -> l2norm -> x[NU+i]
// blocks [ngemm, ...): degree histogram over the 1M (u,it) edges (4 edges/thread).
// The two are independent; fusing overlaps VALU-bound GEMM with latency-bound atomics.
__global__ __launch_bounds__(256) void k_gemm_hist(const float* __restrict__ A,
                                                   const float* __restrict__ W,
                                                   const float* __restrict__ Bb,
                                                   float* __restrict__ x,
                                                   int NI, int DF, int NU, int ngemm,
                                                   const int* __restrict__ eu,
                                                   const int* __restrict__ ei, int E,
                                                   int* __restrict__ deg) {
    __shared__ float Ws[32][64];
    __shared__ float As[64][36];  // pad 32->36: conflict-free b128 reads

    if ((int)blockIdx.x >= ngemm) {
        // ---- histogram path (node ids are global: users 0..NU, items NU..n) ----
        int b = blockIdx.x - ngemm;
        int e0 = (b * 256 + threadIdx.x) * 4;
        if (e0 + 3 < E) {
            int4 uu = *(const int4*)&eu[e0];
            int4 ii = *(const int4*)&ei[e0];
            atomicAdd(&deg[uu.x], 1); atomicAdd(&deg[uu.y], 1);
            atomicAdd(&deg[uu.z], 1); atomicAdd(&deg[uu.w], 1);
            atomicAdd(&deg[ii.x], 1); atomicAdd(&deg[ii.y], 1);
            atomicAdd(&deg[ii.z], 1); atomicAdd(&deg[ii.w], 1);
        } else {
            for (int e = e0; e < E; ++e) {
                atomicAdd(&deg[eu[e]], 1);
                atomicAdd(&deg[ei[e]], 1);
            }
        }
        return;
    }

    // ---- GEMM path ----
    const int tid = threadIdx.x;
    const int tc = tid & 15, tr = tid >> 4;
    const int row0 = blockIdx.x * 64;
    const int c0 = tc * 4;

    float acc[4][4];
#pragma unroll
    for (int r = 0; r < 4; ++r)
#pragma unroll
        for (int c = 0; c < 4; ++c) acc[r][c] = 0.f;

    for (int k0 = 0; k0 < DF; k0 += 32) {
        __syncthreads();
#pragma unroll
        for (int p = 0; p < 2; ++p) {
            int idx = p * 256 + tid;
            int r = idx >> 4, c4 = (idx & 15) * 4;
            *(float4*)&Ws[r][c4] = *(const float4*)&W[(size_t)(k0 + r) * 64 + c4];
        }
#pragma unroll
        for (int p = 0; p < 2; ++p) {
            int lin = p * 256 + tid;
            int r = lin >> 3, c4 = (lin & 7) * 4;
            int gr = row0 + r;
            if (gr >= NI) gr = NI - 1;
            *(float4*)&As[r][c4] = *(const float4*)&A[(size_t)gr * DF + k0 + c4];
        }
        __syncthreads();
#pragma unroll
        for (int kk = 0; kk < 32; kk += 4) {
            float b[4][4];
#pragma unroll
            for (int i = 0; i < 4; ++i)
                *(float4*)b[i] = *(const float4*)&Ws[kk + i][c0];
#pragma unroll
            for (int rr = 0; rr < 4; ++rr) {
                float a[4];
                *(float4*)a = *(const float4*)&As[rr * 16 + tr][kk];
#pragma unroll
                for (int i = 0; i < 4; ++i)
#pragma unroll
                    for (int c = 0; c < 4; ++c)
                        acc[rr][c] = fmaf(a[i], b[i][c], acc[rr][c]);
            }
        }
    }

    float bias[4];
    *(float4*)bias = *(const float4*)&Bb[c0];

#pragma unroll
    for (int rr = 0; rr < 4; ++rr) {
        int gr = row0 + rr * 16 + tr;
        float v[4];
#pragma unroll
        for (int c = 0; c < 4; ++c) {
            float t = acc[rr][c] + bias[c];
            v[c] = t >= 0.f ? t : 0.01f * t;  // leaky_relu
        }
        float ss = v[0] * v[0] + v[1] * v[1] + v[2] * v[2] + v[3] * v[3];
#pragma unroll
        for (int off = 1; off < 16; off <<= 1) ss += __shfl_xor(ss, off, 64);
        float scale = 1.f / fmaxf(sqrtf(ss), 1e-12f);
        if (gr < NI) {
            float4 o;
            o.x = v[0] * scale; o.y = v[1] * scale; o.z = v[2] * scale; o.w = v[3] * scale;
            *(float4*)&x[(size_t)(NU + gr) * 64 + c0] = o;
        }
    }
}

// -------------------- scans (over concatenated deg[0..n)) --------------------
__global__ void k_scan_sums(const int* __restrict__ deg, int m, int* __restrict__ sums) {
    __shared__ int sm[256];
    int t = threadIdx.x;
    int base = blockIdx.x * 2048 + t * 8;
    int s = 0;
#pragma unroll
    for (int i = 0; i < 8; ++i) {
        int idx = base + i;
        if (idx < m) s += deg[idx];
    }
    sm[t] = s;
    __syncthreads();
    for (int off = 128; off > 0; off >>= 1) {
        if (t < off) sm[t] += sm[t + off];
        __syncthreads();
    }
    if (t == 0) sums[blockIdx.x] = sm[0];
}

__global__ void k_scan_offsets(int* __restrict__ sums, int nb, int* __restrict__ rp_last) {
    if (threadIdx.x == 0 && blockIdx.x == 0) {
        int run = 0;
        for (int i = 0; i < nb; ++i) { int t = sums[i]; sums[i] = run; run += t; }
        *rp_last = run;
    }
}

__global__ void k_scan_apply(const int* __restrict__ deg, int m, const int* __restrict__ sums,
                             int* __restrict__ rp, int* __restrict__ cur) {
    __shared__ int sm[256];
    int t = threadIdx.x;
    int base = blockIdx.x * 2048 + t * 8;
    int v[8];
    int s = 0;
#pragma unroll
    for (int i = 0; i < 8; ++i) {
        int idx = base + i;
        v[i] = (idx < m) ? deg[idx] : 0;
        s += v[i];
    }
    sm[t] = s;
    __syncthreads();
    for (int off = 1; off < 256; off <<= 1) {
        int add = (t >= off) ? sm[t - off] : 0;
        __syncthreads();
        sm[t] += add;
        __syncthreads();
    }
    int run = sums[blockIdx.x] + sm[t] - s;
#pragma unroll
    for (int i = 0; i < 8; ++i) {
        int idx = base + i;
        if (idx < m) { rp[idx] = run; cur[idx] = run; run += v[i]; }
    }
}

// -------------------- scatter: both CSR halves in one pass --------------------
// pair[slot] = (src_node, eid). User-dst entries land in [0,EU), item-dst in [EU,2EU)
// (CSR order == node order, users first). 128-thr blocks for CU balance.
__global__ __launch_bounds__(128) void k_scatter2(const int* __restrict__ eu,
                                                  const int* __restrict__ ei, int E,
                                                  int* __restrict__ cur,
                                                  int2* __restrict__ pair, int EU) {
    int e0 = (blockIdx.x * 128 + threadIdx.x) * 4;
    if (e0 + 3 < E) {
        int4 uu = *(const int4*)&eu[e0];
        int4 ii = *(const int4*)&ei[e0];
        int uarr[4] = {uu.x, uu.y, uu.z, uu.w};
        int iarr[4] = {ii.x, ii.y, ii.z, ii.w};
        int su[4], si[4];
#pragma unroll
        for (int k = 0; k < 4; ++k) su[k] = atomicAdd(&cur[uarr[k]], 1);
#pragma unroll
        for (int k = 0; k < 4; ++k) si[k] = atomicAdd(&cur[iarr[k]], 1);
#pragma unroll
        for (int k = 0; k < 4; ++k) pair[su[k]] = make_int2(iarr[k], e0 + k);
#pragma unroll
        for (int k = 0; k < 4; ++k) pair[si[k]] = make_int2(uarr[k], EU + e0 + k);
    } else {
        for (int e = e0; e < E; ++e) {
            int uu = eu[e], ii = ei[e];
            int su = atomicAdd(&cur[uu], 1);
            pair[su] = make_int2(ii, e);
            int si = atomicAdd(&cur[ii], 1);
            pair[si] = make_int2(uu, EU + e);
        }
    }
}

// -------------------- user routing: l2norm(pref) + 3 fused iterations ------
// wave per user; 4 groups of 16 lanes; group g does edges j0+g, +4, ...;
// 2-deep software pipeline on the row gathers (L2/L3 latency ~300-500cy).
__global__ __launch_bounds__(256) void k_refine_user3(const float* __restrict__ P,
                                                      float* __restrict__ x,
                                                      const int* __restrict__ rp,
                                                      const int2* __restrict__ pairs, int NU) {
    int u = (int)((blockIdx.x * blockDim.x + threadIdx.x) >> 6);
    int lane = threadIdx.x & 63;
    int g = lane >> 4, l = lane & 15;
    if (u >= NU) return;

    float4 xd = *(const float4*)&P[(size_t)u * 64 + l * 4];
    {   // l2norm(pref)
        float ss = xd.x * xd.x + xd.y * xd.y + xd.z * xd.z + xd.w * xd.w;
        ss = group16_sum(ss);
        float sc = 1.f / fmaxf(sqrtf(ss), 1e-12f);
        xd.x *= sc; xd.y *= sc; xd.z *= sc; xd.w *= sc;
    }
    const int j0 = rp[u], j1 = rp[u + 1];

#pragma unroll 1
    for (int it = 0; it < 3; ++it) {
        float s = 0.f;
        float4 acc = {0.f, 0.f, 0.f, 0.f};
        int j = j0 + g;
        bool vA = j < j1, vB = j + 4 < j1;
        float4 xsA = {0.f, 0.f, 0.f, 0.f}, xsB = {0.f, 0.f, 0.f, 0.f};
        if (vA) xsA = *(const float4*)&x[(size_t)pairs[j].x * 64 + l * 4];
        if (vB) xsB = *(const float4*)&x[(size_t)pairs[j + 4].x * 64 + l * 4];
        while (vA) {
            bool vC = j + 8 < j1;
            float4 xsC = {0.f, 0.f, 0.f, 0.f};
            if (vC) xsC = *(const float4*)&x[(size_t)pairs[j + 8].x * 64 + l * 4];
            float d = xd.x * xsA.x + xd.y * xsA.y + xd.z * xsA.z + xd.w * xsA.w;
            d = group16_sum(d);
            float e = __expf(d);
            s += e;
            acc.x = fmaf(e, xsA.x, acc.x); acc.y = fmaf(e, xsA.y, acc.y);
            acc.z = fmaf(e, xsA.z, acc.z); acc.w = fmaf(e, xsA.w, acc.w);
            xsA = xsB; vA = vB; xsB = xsC; vB = vC; j += 4;
        }
        s += __shfl_xor(s, 16, 64); s += __shfl_xor(s, 32, 64);
        acc.x += __shfl_xor(acc.x, 16, 64); acc.x += __shfl_xor(acc.x, 32, 64);
        acc.y += __shfl_xor(acc.y, 16, 64); acc.y += __shfl_xor(acc.y, 32, 64);
        acc.z += __shfl_xor(acc.z, 16, 64); acc.z += __shfl_xor(acc.z, 32, 64);
        acc.w += __shfl_xor(acc.w, 16, 64); acc.w += __shfl_xor(acc.w, 32, 64);
        float inv = 1.f / (s + 1e-16f);
        float4 v;
        v.x = xd.x + acc.x * inv; v.y = xd.y + acc.y * inv;
        v.z = xd.z + acc.z * inv; v.w = xd.w + acc.w * inv;
        float ss = v.x * v.x + v.y * v.y + v.z * v.z + v.w * v.w;
        ss = group16_sum(ss);
        float sc = 1.f / fmaxf(sqrtf(ss), 1e-12f);
        xd.x = v.x * sc; xd.y = v.y * sc; xd.z = v.z * sc; xd.w = v.w * sc;
    }
    if (g == 0) *(float4*)&x[(size_t)u * 64 + l * 4] = xd;
}

// -------------------- final refine over full adj (unified CSR) --------------
__global__ __launch_bounds__(256) void k_refine_final(const float* __restrict__ x,
                                                      const int* __restrict__ rp,
                                                      const int2* __restrict__ pairs, int n,
                                                      float* __restrict__ out,
                                                      float* __restrict__ alpha,
                                                      float* __restrict__ sinv) {
    int d = (int)((blockIdx.x * blockDim.x + threadIdx.x) >> 6);
    int lane = threadIdx.x & 63;
    int g = lane >> 4, l = lane & 15;
    if (d >= n) return;

    const int j0 = rp[d], j1 = rp[d + 1];
    float4 xd = *(const float4*)&x[(size_t)d * 64 + l * 4];

    float s = 0.f;
    float4 acc = {0.f, 0.f, 0.f, 0.f};
    int j = j0 + g;
    bool vA = j < j1, vB = j + 4 < j1;
    float4 xsA = {0.f, 0.f, 0.f, 0.f}, xsB = {0.f, 0.f, 0.f, 0.f};
    int eA = 0, eB = 0;
    if (vA) { int2 p = pairs[j];     eA = p.y; xsA = *(const float4*)&x[(size_t)p.x * 64 + l * 4]; }
    if (vB) { int2 p = pairs[j + 4]; eB = p.y; xsB = *(const float4*)&x[(size_t)p.x * 64 + l * 4]; }
    while (vA) {
        bool vC = j + 8 < j1;
        float4 xsC = {0.f, 0.f, 0.f, 0.f};
        int eC = 0;
        if (vC) { int2 p = pairs[j + 8]; eC = p.y; xsC = *(const float4*)&x[(size_t)p.x * 64 + l * 4]; }
        float dt = xd.x * xsA.x + xd.y * xsA.y + xd.z * xsA.z + xd.w * xsA.w;
        dt = group16_sum(dt);
        float e = __expf(dt);
        s += e;
        acc.x = fmaf(e, xsA.x, acc.x); acc.y = fmaf(e, xsA.y, acc.y);
        acc.z = fmaf(e, xsA.z, acc.z); acc.w = fmaf(e, xsA.w, acc.w);
        if (l == 0) alpha[eA] = e;  // unscaled; scaled by k_alpha_scale4
        xsA = xsB; eA = eB; vA = vB; xsB = xsC; eB = eC; vB = vC; j += 4;
    }
    s += __shfl_xor(s, 16, 64); s += __shfl_xor(s, 32, 64);
    acc.x += __shfl_xor(acc.x, 16, 64); acc.x += __shfl_xor(acc.x, 32, 64);
    acc.y += __shfl_xor(acc.y, 16, 64); acc.y += __shfl_xor(acc.y, 32, 64);
    acc.z += __shfl_xor(acc.z, 16, 64); acc.z += __shfl_xor(acc.z, 32, 64);
    acc.w += __shfl_xor(acc.w, 16, 64); acc.w += __shfl_xor(acc.w, 32, 64);
    float inv = 1.f / (s + 1e-16f);
    if (lane == 0) sinv[d] = inv;
    if (g == 0) {
        float4 xh;
        xh.x = acc.x * inv; xh.y = acc.y * inv; xh.z = acc.z * inv; xh.w = acc.w * inv;
        xh.x = xh.x >= 0.f ? xh.x : 0.01f * xh.x;
        xh.y = xh.y >= 0.f ? xh.y : 0.01f * xh.y;
        xh.z = xh.z >= 0.f ? xh.z : 0.01f * xh.z;
        xh.w = xh.w >= 0.f ? xh.w : 0.01f * xh.w;
        float4 o;
        o.x = xd.x + xh.x; o.y = xd.y + xh.y; o.z = xd.z + xh.z; o.w = xd.w + xh.w;
        *(float4*)&out[(size_t)d * 64 + l * 4] = o;
    }
}

__global__ void k_alpha_scale4(float* __restrict__ alpha, const int* __restrict__ adj_dst,
                               const float* __restrict__ sinv, int E) {
    int e0 = (blockIdx.x * blockDim.x + threadIdx.x) * 4;
    if (e0 + 3 < E) {
        int4 d = *(const int4*)&adj_dst[e0];
        float4 a = *(const float4*)&alpha[e0];
        a.x *= sinv[d.x]; a.y *= sinv[d.y]; a.z *= sinv[d.z]; a.w *= sinv[d.w];
        *(float4*)&alpha[e0] = a;
    } else {
        for (int e = e0; e < E; ++e) alpha[e] *= sinv[adj_dst[e]];
    }
}

// -------------------- orchestration --------------------
extern "C" void kernel_launch(void* const* d_in, const int* in_sizes, int n_in,
                              void* d_out, int out_size, void* d_ws, size_t ws_size,
                              hipStream_t stream) {
    const float* features = (const float*)d_in[0];
    const float* mlp_w    = (const float*)d_in[1];
    const float* mlp_b    = (const float*)d_in[2];
    const float* pref     = (const float*)d_in[3];
    const int*   adj      = (const int*)d_in[4];
    const int*   adj_u    = (const int*)d_in[5];

    const int DC = in_sizes[2];        // 64
    const int DF = in_sizes[1] / DC;   // 2048
    const int NI = in_sizes[0] / DF;   // 30000
    const int NU = in_sizes[3] / DC;   // 50000
    const int E2 = in_sizes[4] / 2;    // 2,000,000
    const int EU = in_sizes[5] / 2;    // 1,000,000
    const int n  = NU + NI;            // 80000

    // workspace layout (8B-aligned arrays first)
    char* w = (char*)d_ws;
    int2* pair    = (int2*)w;  w += (size_t)2 * EU * 8;   // [0,EU)=user CSR, [EU,2EU)=item CSR
    float* x      = (float*)w; w += (size_t)n * 64 * 4;
    int* rp       = (int*)w;   w += (size_t)(n + 1) * 4;
    int* cur      = (int*)w;   w += (size_t)n * 4;
    int* deg      = (int*)w;   w += (size_t)n * 4;
    int* sums     = (int*)w;   w += 64 * 4;
    float* sinv   = (float*)w; w += (size_t)n * 4;

    hipMemsetAsync(deg, 0, (size_t)n * 4, stream);

    // fused: GEMM (blocks [0,ngemm)) + degree histogram (remaining blocks)
    int ngemm = (NI + 63) / 64;
    int nhist = (EU / 4 + 255) / 256;
    k_gemm_hist<<<ngemm + nhist, 256, 0, stream>>>(features, mlp_w, mlp_b, x, NI, DF, NU,
                                                   ngemm, adj_u, adj_u + EU, EU, deg);

    // single scan chain over all n nodes (users then items)
    int nb = (n + 2047) / 2048;
    k_scan_sums<<<nb, 256, 0, stream>>>(deg, n, sums);
    k_scan_offsets<<<1, 64, 0, stream>>>(sums, nb, rp + n);
    k_scan_apply<<<nb, 256, 0, stream>>>(deg, n, sums, rp, cur);

    // one scatter pass builds both CSR halves
    k_scatter2<<<(EU / 4 + 127) / 128, 128, 0, stream>>>(adj_u, adj_u + EU, EU, cur, pair, EU);

    // pref l2norm + 3 routing iterations, fused
    k_refine_user3<<<(NU + 3) / 4, 256, 0, stream>>>(pref, x, rp, pair, NU);

    // final refine + outputs
    float* out   = (float*)d_out;
    float* alpha = out + (size_t)n * 64;
    k_refine_final<<<(n + 3) / 4, 256, 0, stream>>>(x, rp, pair, n, out, alpha, sinv);
    k_alpha_scale4<<<(E2 / 4 + 255) / 256, 256, 0, stream>>>(alpha, adj, sinv, E2);
}